// Round 3
// baseline (384.425 us; speedup 1.0000x reference)
//
#include <hip/hip_runtime.h>
#include <math.h>

// SimRel: out[b][c] = dot(x_b, cls_c) / max(|x_b||cls_c|, 1e-8); 1.0 if cls_c has inf.
// bf16 MFMA tall-skinny GEMM, round-2 structure (LDS-DMA double buffers, manual
// vmcnt, swapped-operand MFMA for vectorized stores) + PERSISTENT BLOCKS:
//   - grid = 512 blocks (exactly 2 resident/CU at 64KB LDS), each does 4
//     consecutive 128-row chunks -> B-staging paid 512x not 2048x, and no
//     separate prep kernel (launch-latency-dominated: ~4-6us for 0.3us work).
//   - cross-chunk seamless pipeline: at ks==7 issue NEXT chunk's window-0 DMA
//     and wait vmcnt(4) (never drain to 0 mid-kernel). At ks==0 of chunks j>0,
//     wait vmcnt(12) = the 12 vmem ops issued after the needed window
//     (8 epilogue stores + 4 next-window loads) -- conservative by in-order
//     vmcnt retirement, independent of store-ack latency.
//   - class norms computed during staging (fp32, from CLS) -> LDS table.

typedef __attribute__((ext_vector_type(8))) short bf16x8;   // 8 bf16 (4 VGPRs)
typedef __attribute__((ext_vector_type(4))) float f32x4;    // MFMA C/D

#define EPS 1e-8f

__device__ __forceinline__ short f2bf(float f) {
  // fp32 -> bf16 round-to-nearest-even (preserves inf)
  union { float f; unsigned u; } v; v.f = f;
  unsigned r = v.u + 0x7fffu + ((v.u >> 16) & 1u);
  return (short)(r >> 16);
}

// async 16B/lane global->LDS DMA; lds base wave-uniform, lane L lands at +L*16;
// global src address is PER-LANE.
__device__ __forceinline__ void dma16(const void* g, void* l) {
  __builtin_amdgcn_global_load_lds(
      (const __attribute__((address_space(1))) void*)g,
      (__attribute__((address_space(3))) void*)l, 16, 0, 0);
}

__global__ __launch_bounds__(256) void simrel_kernel(
    const float* __restrict__ X,    // Brows x 256
    const float* __restrict__ CLS,  // 64 x 256
    float* __restrict__ OUT)        // Brows x 64
{
  // A: [wave][buf2][mti2][h2][lane64][4 floats] = 32 KB (fp32, DMA-filled)
  __shared__ __align__(16) float Abuf[4 * 2048];
  // B: [ks8][nt4][lane64][8 bf16] = 32 KB
  __shared__ __align__(16) short Bfrag[8 * 4 * 64 * 8];
  __shared__ __align__(16) float CNlds[64];  // class norms, -1 => inf sentinel

  const int tid  = threadIdx.x;
  const int wave = tid >> 6;
  const int lane = tid & 63;
  const int m    = lane & 15;
  const int quad = lane >> 4;

  size_t rowbase = (size_t)blockIdx.x * 512 + (size_t)wave * 32;

  // lane's global gather base per (mti, h); k-step window ks adds ks*32 floats
  const float* gb[2][2];
#pragma unroll
  for (int mti = 0; mti < 2; ++mti)
#pragma unroll
    for (int h = 0; h < 2; ++h)
      gb[mti][h] = X + (rowbase + mti * 16 + m) * 256 + h * 16 + quad * 4;

  float* abase = &Abuf[wave * 2048];  // wave-private 8KB (2 buffers x 4KB)

  // prime chunk-0 window-0 FIRST: HBM fetch in flight while we stage B below
#pragma unroll
  for (int mti = 0; mti < 2; ++mti)
#pragma unroll
    for (int h = 0; h < 2; ++h)
      dma16(gb[mti][h], abase + (mti * 2 + h) * 256);

  // ---- stage B (class_avgs) -> bf16 fragment layout + class norms (once) ----
  {
    const int c  = tid >> 2;       // class 0..63
    const int qq = tid & 3;        // 64-float quarter of the class row
    const float4* src = (const float4*)CLS + c * 64 + qq * 16;
    float s = 0.f;
    float fl = 0.f;
#pragma unroll
    for (int i = 0; i < 16; ++i) {
      float4 v = src[i];
      s += v.x * v.x + v.y * v.y + v.z * v.z + v.w * v.w;
      if (isinf(v.x) || isinf(v.y) || isinf(v.z) || isinf(v.w)) fl = 1.f;
      // MFMA fragment layout (k-slot map: slot j of quad q <-> k=(j>>2)*16+q*4+(j&3))
      const int wabs = qq * 64 + i * 4;
      const int ks = wabs >> 5;
      const int w0 = wabs & 31;
      const int h  = w0 >> 4;
      const int qd = (w0 >> 2) & 3;
      const int lb = (qd << 4) | (c & 15);
      const int nt = c >> 4;
      *(short4*)&Bfrag[((ks * 4 + nt) * 64 + lb) * 8 + h * 4] =
          make_short4(f2bf(v.x), f2bf(v.y), f2bf(v.z), f2bf(v.w));
    }
    // reduce across the 4 threads sharing a class (consecutive lanes)
    s  += __shfl_xor(s, 1);  s  += __shfl_xor(s, 2);
    fl += __shfl_xor(fl, 1); fl += __shfl_xor(fl, 2);
    if (qq == 0) CNlds[c] = (fl > 0.f || !isfinite(s)) ? -1.0f : sqrtf(s);
  }

  __syncthreads();  // barrier + vmcnt drain: Bfrag, CNlds, window-0 all resident

  // class-norm table: lane needs classes nt*16 + quad*4 + r (broadcast reads)
  f32x4 cnq[4];
#pragma unroll
  for (int nt = 0; nt < 4; ++nt)
    cnq[nt] = *(const f32x4*)&CNlds[nt * 16 + quad * 4];

  for (int j = 0; j < 4; ++j) {  // 4 chunks of 128 rows per block
    f32x4 acc[2][4];
#pragma unroll
    for (int mti = 0; mti < 2; ++mti)
#pragma unroll
      for (int nt = 0; nt < 4; ++nt)
        acc[mti][nt] = (f32x4){0.f, 0.f, 0.f, 0.f};
    float ssqr[2] = {0.f, 0.f};

#pragma unroll
    for (int ks = 0; ks < 8; ++ks) {
      if (ks < 7) {
        // issue window ks+1 into the other buffer, then wait for window ks
        const int nb = (ks + 1) & 1;
#pragma unroll
        for (int mti = 0; mti < 2; ++mti)
#pragma unroll
          for (int h = 0; h < 2; ++h)
            dma16(gb[mti][h] + (ks + 1) * 32, abase + (nb * 4 + mti * 2 + h) * 256);
        if (ks == 0) {
          if (j != 0) {
            // queue (oldest->newest): [w0 4][stores 8][w1 4] -> need w0 done
            asm volatile("s_waitcnt vmcnt(12)" ::: "memory");
          } else {
            asm volatile("s_waitcnt vmcnt(4)" ::: "memory");
          }
        } else {
          asm volatile("s_waitcnt vmcnt(4)" ::: "memory");
        }
      } else {
        if (j != 3) {
          // seamless: issue NEXT chunk's window 0 into buf0 (last read at ks=6)
#pragma unroll
          for (int mti = 0; mti < 2; ++mti)
#pragma unroll
            for (int h = 0; h < 2; ++h)
              dma16(gb[mti][h] + 128 * 256, abase + (mti * 2 + h) * 256);
          asm volatile("s_waitcnt vmcnt(4)" ::: "memory");
        } else {
          asm volatile("s_waitcnt vmcnt(0)" ::: "memory");
        }
      }
      const int cb = ks & 1;

      bf16x8 bw[4];
#pragma unroll
      for (int nt = 0; nt < 4; ++nt)
        bw[nt] = *(const bf16x8*)&Bfrag[((ks * 4 + nt) * 64 + lane) * 8];

#pragma unroll
      for (int mti = 0; mti < 2; ++mti) {
        float4 a0 = *(const float4*)(abase + (cb * 4 + mti * 2 + 0) * 256 + lane * 4);
        float4 a1 = *(const float4*)(abase + (cb * 4 + mti * 2 + 1) * 256 + lane * 4);
        ssqr[mti] += a0.x * a0.x + a0.y * a0.y + a0.z * a0.z + a0.w * a0.w +
                     a1.x * a1.x + a1.y * a1.y + a1.z * a1.z + a1.w * a1.w;
        bf16x8 af;
        af[0] = f2bf(a0.x); af[1] = f2bf(a0.y); af[2] = f2bf(a0.z); af[3] = f2bf(a0.w);
        af[4] = f2bf(a1.x); af[5] = f2bf(a1.y); af[6] = f2bf(a1.z); af[7] = f2bf(a1.w);
        // SWAPPED operands: D rows = classes, D cols = X-rows.
        // Lane (m,quad), reg r of acc[mti][nt] = OUT[rowbase+mti*16+m][nt*16+quad*4+r]
#pragma unroll
        for (int nt = 0; nt < 4; ++nt)
          acc[mti][nt] =
              __builtin_amdgcn_mfma_f32_16x16x32_bf16(bw[nt], af, acc[mti][nt], 0, 0, 0);
      }
    }

    // ---- epilogue for this chunk: norms, divide, vectorized store ----
#pragma unroll
    for (int mti = 0; mti < 2; ++mti) {
      float s = ssqr[mti];
      s += __shfl_xor(s, 16);
      s += __shfl_xor(s, 32);
      const float xn = sqrtf(s);  // norm of row rowbase + mti*16 + m
      const size_t row = rowbase + mti * 16 + m;
#pragma unroll
      for (int nt = 0; nt < 4; ++nt) {
        f32x4 o;
#pragma unroll
        for (int r = 0; r < 4; ++r) {
          const float cn = cnq[nt][r];
          const float d = fmaxf(xn * cn, EPS);
          const float v = acc[mti][nt][r] * __builtin_amdgcn_rcpf(d);
          o[r] = (cn < 0.f) ? 1.0f : v;  // sentinel: class had inf
        }
        *(f32x4*)&OUT[row * 64 + nt * 16 + quad * 4] = o;  // 16B aligned
      }
    }

    rowbase += 128;
#pragma unroll
    for (int mti = 0; mti < 2; ++mti)
#pragma unroll
      for (int h = 0; h < 2; ++h)
        gb[mti][h] += 128 * 256;
  }
}

extern "C" void kernel_launch(void* const* d_in, const int* in_sizes, int n_in,
                              void* d_out, int out_size, void* d_ws, size_t ws_size,
                              hipStream_t stream) {
  (void)n_in; (void)d_ws; (void)ws_size; (void)out_size;
  const float* X   = (const float*)d_in[0];   // inputs, fp32 B x 256
  // d_in[1] = labels (unused by the reference output)
  const float* CLS = (const float*)d_in[2];   // class_avgs, fp32 64 x 256
  float* OUT = (float*)d_out;

  const int Brows  = in_sizes[0] / 256;       // 262144
  const int blocks = Brows / 512;             // 512 persistent blocks (2/CU), 4 chunks each
  simrel_kernel<<<blocks, 256, 0, stream>>>(X, CLS, OUT);
}